// Round 1
// baseline (7721.848 us; speedup 1.0000x reference)
//
#include <hip/hip_runtime.h>
#include <hip/hip_bf16.h>
#include <hip/hip_fp16.h>
#include <hip/hip_cooperative_groups.h>

#define B_ 128
#define S_ 128
#define I_ 300
#define IP_ 320
#define H_ 1024
#define C_ 2

typedef __attribute__((ext_vector_type(8))) short short8;
typedef __attribute__((ext_vector_type(4))) float f32x4;

__device__ inline short f2b(float f) {
    union { __hip_bfloat16 h; unsigned short s; } cv;
    cv.h = __float2bfloat16(f);
    return (short)cv.s;
}

__global__ __launch_bounds__(256) void prep_bias(
    const float* __restrict__ b_ih, const float* __restrict__ b_hh,
    float* __restrict__ bias)
{
    int i = blockIdx.x * 256 + threadIdx.x;
    if (i < 4 * H_) bias[i] = b_ih[i] + b_hh[i];
}

// W_ihp bf16 [4096][320], zero-padded cols 300..319
__global__ __launch_bounds__(256) void prep_wih(
    const float* __restrict__ W_ih, unsigned short* __restrict__ Wp)
{
    int idx = blockIdx.x * 256 + threadIdx.x;
    if (idx >= 4096 * IP_) return;
    int row = idx / IP_, k = idx - row * IP_;
    Wp[idx] = (k < I_) ? (unsigned short)f2b(W_ih[row * I_ + k]) : 0;
}

// xe bf16 [S][B][320]: gathered embedding rows, zero-padded
__global__ __launch_bounds__(256) void prep_xe(
    const int* __restrict__ x, const float* __restrict__ embed_W,
    unsigned short* __restrict__ xe)
{
    int idx = blockIdx.x * 256 + threadIdx.x;
    if (idx >= S_ * B_ * IP_) return;
    int k = idx % IP_;
    int tb = idx / IP_;
    int b = tb % B_, t = tb / B_;
    int row = x[b * S_ + t];
    xe[idx] = (k < I_) ? (unsigned short)f2b(embed_W[(size_t)row * I_ + k]) : 0;
}

// Wfrag: W_hh in per-lane MFMA B-fragment order (R6/R7-proven layout)
__global__ __launch_bounds__(256) void prep_wfrag(
    const float* __restrict__ W_hh, unsigned short* __restrict__ Wfrag)
{
    int idx = blockIdx.x * 256 + threadIdx.x;   // 0 .. 524287
    const int lane = idx & 63;
    const int f    = (idx >> 6) & 31;
    const int wid  = (idx >> 11) & 3;
    const int ug   = idx >> 13;
    const int row  = wid * H_ + ug * 16 + (lane & 15);
    const int k0   = f * 32 + (lane >> 4) * 8;
    const float* src = W_hh + (size_t)row * H_ + k0;
    unsigned short* dst = Wfrag + (size_t)idx * 8;
#pragma unroll
    for (int j = 0; j < 8; ++j)
        dst[j] = (unsigned short)f2b(src[j]);
}

// ---------------------------------------------------------------------------
// gates in FRAGMENT layout (half bits):
//   idx = t*524288 + bx*16384 + nt*2048 + fr*128 + fq*32 + wp*8 + mt*4 + r
//   holds gate for col n = bx*128+nt*16+fr, batch m = wp*32+mt*16+fq*4+r.
// Producer stores one coalesced 16-B short8 per nt (mt 0,1 packed);
// consumer (persistent kernel, wave=gate wid, block ug,bg) reads its 8 values
// with ONE 16-B load: bx = wid*8+(ug>>3), nt = ug&7, wp = bg.
// ---------------------------------------------------------------------------
__global__ __launch_bounds__(256) void gemm_ih(
    const unsigned short* __restrict__ xe,   // [S][B][320] bf16
    const unsigned short* __restrict__ Wp,   // [4096][320] bf16
    const float* __restrict__ bias,          // [4096]
    unsigned short* __restrict__ gates)      // frag layout, half bits
{
    const int tid = threadIdx.x;
    const int wid = tid >> 6, lane = tid & 63;
    const int fr = lane & 15, fq = lane >> 4;
    const int bx = blockIdx.x;            // n-tile base bx*128
    const int t  = blockIdx.y;

    __shared__ alignas(16) unsigned short As_[128][40];
    __shared__ alignas(16) unsigned short Bs_[128][40];

    const int sr = tid >> 1;
    const int sc = (tid & 1) * 16;
    const unsigned short* arow = xe + ((size_t)t * B_ + sr) * IP_;
    const unsigned short* brow = Wp + (size_t)(bx * 128 + sr) * IP_;

    f32x4 acc[2][8] = {};

    for (int kc = 0; kc < 10; ++kc) {
        __syncthreads();
        const int k0 = kc * 32 + sc;
        *(short8*)&As_[sr][sc]     = *(const short8*)(arow + k0);
        *(short8*)&As_[sr][sc + 8] = *(const short8*)(arow + k0 + 8);
        *(short8*)&Bs_[sr][sc]     = *(const short8*)(brow + k0);
        *(short8*)&Bs_[sr][sc + 8] = *(const short8*)(brow + k0 + 8);
        __syncthreads();
        short8 bfrag[8];
#pragma unroll
        for (int nt = 0; nt < 8; ++nt)
            bfrag[nt] = *(const short8*)&Bs_[nt * 16 + fr][fq * 8];
#pragma unroll
        for (int mt = 0; mt < 2; ++mt) {
            short8 a = *(const short8*)&As_[wid * 32 + mt * 16 + fr][fq * 8];
#pragma unroll
            for (int nt = 0; nt < 8; ++nt)
                acc[mt][nt] = __builtin_amdgcn_mfma_f32_16x16x32_bf16(
                    a, bfrag[nt], acc[mt][nt], 0, 0, 0);
        }
    }
    // epilogue: one coalesced 16-B store per nt
    unsigned short* gbase = gates + (size_t)t * 524288 + (size_t)bx * 16384
                          + fr * 128 + fq * 32 + wid * 8;
#pragma unroll
    for (int nt = 0; nt < 8; ++nt) {
        const float bs = bias[bx * 128 + nt * 16 + fr];
        short8 pk;
#pragma unroll
        for (int r = 0; r < 4; ++r) {
            pk[r]     = (short)__half_as_ushort(__float2half(acc[0][nt][r] + bs));
            pk[4 + r] = (short)__half_as_ushort(__float2half(acc[1][nt][r] + bs));
        }
        *(short8*)(gbase + nt * 2048) = pk;
    }
}

// ---------------------------------------------------------------------------
// Persistent recurrent kernel: ALL 128 timesteps in ONE cooperative launch.
//   grid (64 ug, 4 bg) = 256 blocks, 256 thr = 4 waves; wave = gate.
//   - W fragments (bfr[32], 128 VGPR) loaded ONCE for all steps
//   - cell state c lives in registers (each thread owns the same (m,u0..u0+1)
//     pair every step) -- no c_state global traffic at all
//   - cross-step h exchange via hs[] global; hs is time-indexed (write t+1,
//     read t) so ONE __threadfence + grid.sync() per step suffices
// ---------------------------------------------------------------------------
__global__ __launch_bounds__(256, 1) void lstm_persistent(
    const unsigned short* __restrict__ Wfrag,
    const unsigned short* __restrict__ gates,   // frag layout, half bits
    __hip_bfloat16* __restrict__ hs)            // [S+1,B,H]
{
    const int tid  = threadIdx.x;
    const int wid  = tid >> 6;            // wave = gate
    const int lane = tid & 63;
    const int ug = blockIdx.x;
    const int bg = blockIdx.y;
    const int n0 = ug * 16;
    const int fr = lane & 15, fq = lane >> 4;
    const int m0g = bg * 32;

    __shared__ alignas(16) unsigned short As[32][1048];  // h slab 32x1024
    __shared__ float Gs[32][65];                          // gate exchange

    // ---- W fragments: 32 coalesced 16B loads straight to registers, ONCE ----
    short8 bfr[32];
    {
        const unsigned short* wf =
            Wfrag + ((size_t)((ug * 4 + wid) * 32) * 64 + lane) * 8;
#pragma unroll
        for (int f = 0; f < 32; ++f)
            bfr[f] = *(const short8*)(wf + (size_t)f * 512);
    }

    // cell-state registers: this thread owns batch row m0g+cm2, units u0,u0+1
    const int cm2 = tid >> 3, up = tid & 7;
    const int u0 = 2 * up;
    float2 cc;
    cc.x = 0.f;
    cc.y = 0.f;

    // fused ih-gates base (per-lane, t-stride 524288)
    const unsigned short* gbase = gates
        + (size_t)(wid * 8 + (ug >> 3)) * 16384
        + (size_t)(ug & 7) * 2048 + fr * 128 + fq * 32 + bg * 8;

    const unsigned short* a0p = &As[fr][fq * 8];
    const unsigned short* a1p = &As[16 + fr][fq * 8];

    cooperative_groups::grid_group grid = cooperative_groups::this_grid();

    for (int t = 0; t < S_; ++t) {
        // ---- issue the fused ih-gate load early (consumed after MFMA) ----
        union { short8 v; __half h[8]; } gih;
        gih.v = *(const short8*)(gbase + (size_t)t * 524288);

        // ---- stage h_prev slab [32][1024] to LDS ----
        {
            const __hip_bfloat16* hprev =
                hs + (size_t)t * (B_ * H_) + (size_t)m0g * H_;
#pragma unroll
            for (int i = 0; i < 16; ++i) {
                const int e = i * 256 + tid;          // 16B-chunk id
                const int r = e >> 7, ch = (e & 127) * 8;
                *(short8*)&As[r][ch] = *(const short8*)(hprev + r * H_ + ch);
            }
        }
        __syncthreads();

        // ---- 64 MFMAs: full K=1024 ----
        f32x4 acc0 = {0.f, 0.f, 0.f, 0.f}, acc1 = {0.f, 0.f, 0.f, 0.f};
#pragma unroll
        for (int f = 0; f < 32; ++f) {
            short8 a0 = *(const short8*)(a0p + f * 32);
            short8 a1 = *(const short8*)(a1p + f * 32);
            acc0 = __builtin_amdgcn_mfma_f32_16x16x32_bf16(a0, bfr[f], acc0, 0, 0, 0);
            acc1 = __builtin_amdgcn_mfma_f32_16x16x32_bf16(a1, bfr[f], acc1, 0, 0, 0);
        }

        // fused add of precomputed ih-gates (+bias)
#pragma unroll
        for (int r = 0; r < 4; ++r) {
            acc0[r] += __half2float(gih.h[r]);
            acc1[r] += __half2float(gih.h[4 + r]);
        }

        // ---- exchange complete gates: Gs[m][gate*16+u] ----
        {
            const int col = wid * 16 + fr;
            const int rb = fq * 4;
#pragma unroll
            for (int r = 0; r < 4; ++r) {
                Gs[rb + r][col]      = acc0[r];
                Gs[16 + rb + r][col] = acc1[r];
            }
        }
        __syncthreads();

        // ---- cell update: reg-resident c, write h tile to hs[t+1] ----
        {
            float gi0 = Gs[cm2][u0],      gi1 = Gs[cm2][u0 + 1];
            float gf0 = Gs[cm2][16 + u0], gf1 = Gs[cm2][16 + u0 + 1];
            float gg0 = Gs[cm2][32 + u0], gg1 = Gs[cm2][32 + u0 + 1];
            float go0 = Gs[cm2][48 + u0], go1 = Gs[cm2][48 + u0 + 1];
            float si0 = 1.f / (1.f + __expf(-gi0));
            float sf0 = 1.f / (1.f + __expf(-gf0));
            float so0 = 1.f / (1.f + __expf(-go0));
            float si1 = 1.f / (1.f + __expf(-gi1));
            float sf1 = 1.f / (1.f + __expf(-gf1));
            float so1 = 1.f / (1.f + __expf(-go1));
            cc.x = sf0 * cc.x + si0 * tanhf(gg0);
            cc.y = sf1 * cc.y + si1 * tanhf(gg1);
            float h0 = so0 * tanhf(cc.x);
            float h1 = so1 * tanhf(cc.y);
            unsigned int hv =
                (unsigned int)(unsigned short)f2b(h0) |
                ((unsigned int)(unsigned short)f2b(h1) << 16);
            unsigned int* dst = (unsigned int*)
                (hs + (size_t)(t + 1) * (B_ * H_) +
                 (size_t)(m0g + cm2) * H_ + n0) + up;
            *dst = hv;
        }

        // make h[t+1] visible device-wide, then step barrier
        __threadfence();
        grid.sync();
    }
}

// ---------------------------------------------------------------------------
// Head: one wave per (b,t): out = h . lin_W^T + lin_b, masked by lengths.
// ---------------------------------------------------------------------------
__global__ __launch_bounds__(256) void final_linear(
    const __hip_bfloat16* __restrict__ hs,
    const float* __restrict__ lin_W,
    const float* __restrict__ lin_b,
    const int* __restrict__ lengths,
    float* __restrict__ out)
{
    const int wid  = threadIdx.x >> 6;
    const int lane = threadIdx.x & 63;
    const int p = blockIdx.x * 4 + wid;
    const int b = p >> 7;
    const int t = p & 127;
    const __hip_bfloat16* h =
        hs + (size_t)(t + 1) * (B_ * H_) + (size_t)b * H_;
    float s0 = 0.f, s1 = 0.f;
#pragma unroll
    for (int i = 0; i < 16; ++i) {
        int n = lane + 64 * i;
        float hv = __bfloat162float(h[n]);
        s0 += hv * lin_W[n];
        s1 += hv * lin_W[H_ + n];
    }
#pragma unroll
    for (int off = 32; off > 0; off >>= 1) {
        s0 += __shfl_down(s0, off);
        s1 += __shfl_down(s1, off);
    }
    if (lane == 0) {
        float* o = out + (size_t)p * 2;
        if (t < lengths[b]) {
            o[0] = s0 + lin_b[0];
            o[1] = s1 + lin_b[1];
        } else {
            o[0] = 1.0f;
            o[1] = 0.0f;
        }
    }
}

extern "C" void kernel_launch(void* const* d_in, const int* in_sizes, int n_in,
                              void* d_out, int out_size, void* d_ws,
                              size_t ws_size, hipStream_t stream) {
    const int* x              = (const int*)d_in[0];
    const int* lengths        = (const int*)d_in[1];
    const float* embed_W      = (const float*)d_in[2];
    const float* W_ih         = (const float*)d_in[3];
    const float* W_hh         = (const float*)d_in[4];
    const float* b_ih         = (const float*)d_in[5];
    const float* b_hh         = (const float*)d_in[6];
    const float* lin_W        = (const float*)d_in[7];
    const float* lin_b        = (const float*)d_in[8];
    float* out                = (float*)d_out;

    // ws layout (same footprint as R7; c_state slot now unused):
    //   hs bf16 [S+1,B,H]      @ 0            (33,816,576)
    //   gates half (frag)      @ 33,816,576   (134,217,728)
    //   bias fp32 [4096]       @ 168,034,304  (16,384)
    //   Wfrag bf16             @ 168,050,688  (8,388,608)
    //   xe bf16 [S,B,320]      @ hs+262,144   (10,485,760) [alias, consumed
    //   W_ihp bf16 [4096,320]  @ hs+10,747,904 (2,621,440)  before steps]
    char* ws = (char*)d_ws;
    __hip_bfloat16* hs    = (__hip_bfloat16*)(ws + 0);
    unsigned short* gates = (unsigned short*)(ws + 33816576);
    float* bias           = (float*)(ws + 168034304);
    unsigned short* Wfrag = (unsigned short*)(ws + 168050688);
    unsigned short* xe    = (unsigned short*)(ws + 262144);
    unsigned short* Wp    = (unsigned short*)(ws + 10747904);

    prep_bias<<<16, 256, 0, stream>>>(b_ih, b_hh, bias);
    prep_wih<<<(4096 * IP_ + 255) / 256, 256, 0, stream>>>(W_ih, Wp);
    prep_xe<<<(S_ * B_ * IP_ + 255) / 256, 256, 0, stream>>>(x, embed_W, xe);
    prep_wfrag<<<2048, 256, 0, stream>>>(W_hh, Wfrag);
    (void)hipMemsetAsync(hs, 0, (size_t)B_ * H_ * sizeof(__hip_bfloat16), stream);

    gemm_ih<<<dim3(32, 128), 256, 0, stream>>>(xe, Wp, bias, gates);

    // one cooperative launch for the whole recurrence
    {
        void* kargs[3];
        kargs[0] = (void*)&Wfrag;
        kargs[1] = (void*)&gates;
        kargs[2] = (void*)&hs;
        (void)hipLaunchCooperativeKernel((const void*)lstm_persistent,
                                         dim3(64, 4), dim3(256, 1, 1),
                                         kargs, 0, stream);
    }

    final_linear<<<dim3((B_ * S_) / 4), 256, 0, stream>>>(
        hs, lin_W, lin_b, lengths, out);
}

// Round 2
// 1591.852 us; speedup vs baseline: 4.8509x; 4.8509x over previous
//
#include <hip/hip_runtime.h>
#include <hip/hip_bf16.h>
#include <hip/hip_fp16.h>

#define B_ 128
#define S_ 128
#define I_ 300
#define IP_ 320
#define H_ 1024
#define C_ 2

typedef __attribute__((ext_vector_type(8))) short short8;
typedef __attribute__((ext_vector_type(4))) float f32x4;

__device__ inline short f2b(float f) {
    union { __hip_bfloat16 h; unsigned short s; } cv;
    cv.h = __float2bfloat16(f);
    return (short)cv.s;
}

__global__ __launch_bounds__(256) void prep_bias(
    const float* __restrict__ b_ih, const float* __restrict__ b_hh,
    float* __restrict__ bias)
{
    int i = blockIdx.x * 256 + threadIdx.x;
    if (i < 4 * H_) bias[i] = b_ih[i] + b_hh[i];
}

// W_ihp bf16 [4096][320], zero-padded cols 300..319
__global__ __launch_bounds__(256) void prep_wih(
    const float* __restrict__ W_ih, unsigned short* __restrict__ Wp)
{
    int idx = blockIdx.x * 256 + threadIdx.x;
    if (idx >= 4096 * IP_) return;
    int row = idx / IP_, k = idx - row * IP_;
    Wp[idx] = (k < I_) ? (unsigned short)f2b(W_ih[row * I_ + k]) : 0;
}

// xe bf16 [S][B][320]: gathered embedding rows, zero-padded
__global__ __launch_bounds__(256) void prep_xe(
    const int* __restrict__ x, const float* __restrict__ embed_W,
    unsigned short* __restrict__ xe)
{
    int idx = blockIdx.x * 256 + threadIdx.x;
    if (idx >= S_ * B_ * IP_) return;
    int k = idx % IP_;
    int tb = idx / IP_;
    int b = tb % B_, t = tb / B_;
    int row = x[b * S_ + t];
    xe[idx] = (k < I_) ? (unsigned short)f2b(embed_W[(size_t)row * I_ + k]) : 0;
}

// Wfrag: W_hh in per-lane MFMA B-fragment order (R6/R7-proven layout)
__global__ __launch_bounds__(256) void prep_wfrag(
    const float* __restrict__ W_hh, unsigned short* __restrict__ Wfrag)
{
    int idx = blockIdx.x * 256 + threadIdx.x;   // 0 .. 524287
    const int lane = idx & 63;
    const int f    = (idx >> 6) & 31;
    const int wid  = (idx >> 11) & 3;
    const int ug   = idx >> 13;
    const int row  = wid * H_ + ug * 16 + (lane & 15);
    const int k0   = f * 32 + (lane >> 4) * 8;
    const float* src = W_hh + (size_t)row * H_ + k0;
    unsigned short* dst = Wfrag + (size_t)idx * 8;
#pragma unroll
    for (int j = 0; j < 8; ++j)
        dst[j] = (unsigned short)f2b(src[j]);
}

// ---------------------------------------------------------------------------
// gates in FRAGMENT layout (half bits):
//   idx = t*524288 + bx*16384 + nt*2048 + fr*128 + fq*32 + wp*8 + mt*4 + r
//   holds gate for col n = bx*128+nt*16+fr, batch m = wp*32+mt*16+fq*4+r.
// ---------------------------------------------------------------------------
__global__ __launch_bounds__(256) void gemm_ih(
    const unsigned short* __restrict__ xe,   // [S][B][320] bf16
    const unsigned short* __restrict__ Wp,   // [4096][320] bf16
    const float* __restrict__ bias,          // [4096]
    unsigned short* __restrict__ gates)      // frag layout, half bits
{
    const int tid = threadIdx.x;
    const int wid = tid >> 6, lane = tid & 63;
    const int fr = lane & 15, fq = lane >> 4;
    const int bx = blockIdx.x;            // n-tile base bx*128
    const int t  = blockIdx.y;

    __shared__ alignas(16) unsigned short As_[128][40];
    __shared__ alignas(16) unsigned short Bs_[128][40];

    const int sr = tid >> 1;
    const int sc = (tid & 1) * 16;
    const unsigned short* arow = xe + ((size_t)t * B_ + sr) * IP_;
    const unsigned short* brow = Wp + (size_t)(bx * 128 + sr) * IP_;

    f32x4 acc[2][8] = {};

    for (int kc = 0; kc < 10; ++kc) {
        __syncthreads();
        const int k0 = kc * 32 + sc;
        *(short8*)&As_[sr][sc]     = *(const short8*)(arow + k0);
        *(short8*)&As_[sr][sc + 8] = *(const short8*)(arow + k0 + 8);
        *(short8*)&Bs_[sr][sc]     = *(const short8*)(brow + k0);
        *(short8*)&Bs_[sr][sc + 8] = *(const short8*)(brow + k0 + 8);
        __syncthreads();
        short8 bfrag[8];
#pragma unroll
        for (int nt = 0; nt < 8; ++nt)
            bfrag[nt] = *(const short8*)&Bs_[nt * 16 + fr][fq * 8];
#pragma unroll
        for (int mt = 0; mt < 2; ++mt) {
            short8 a = *(const short8*)&As_[wid * 32 + mt * 16 + fr][fq * 8];
#pragma unroll
            for (int nt = 0; nt < 8; ++nt)
                acc[mt][nt] = __builtin_amdgcn_mfma_f32_16x16x32_bf16(
                    a, bfrag[nt], acc[mt][nt], 0, 0, 0);
        }
    }
    // epilogue: one coalesced 16-B store per nt
    unsigned short* gbase = gates + (size_t)t * 524288 + (size_t)bx * 16384
                          + fr * 128 + fq * 32 + wid * 8;
#pragma unroll
    for (int nt = 0; nt < 8; ++nt) {
        const float bs = bias[bx * 128 + nt * 16 + fr];
        short8 pk;
#pragma unroll
        for (int r = 0; r < 4; ++r) {
            pk[r]     = (short)__half_as_ushort(__float2half(acc[0][nt][r] + bs));
            pk[4 + r] = (short)__half_as_ushort(__float2half(acc[1][nt][r] + bs));
        }
        *(short8*)(gbase + nt * 2048) = pk;
    }
}

// ---------------------------------------------------------------------------
// Persistent recurrent kernel with HAND-ROLLED per-bg barriers.
//   grid (64 ug, 4 bg) = 256 blocks, 256 thr = 4 waves; wave = gate.
//   - W fragments (bfr[32], 128 VGPR) loaded ONCE for all steps
//   - c state in registers; no c_state global traffic
//   - h[t+1] written with relaxed AGENT-scope atomic stores (cache-bypassing,
//     land at coherent LLC), drained with vmcnt(0), then a relaxed agent
//     atomicAdd arrival on a per-bg monotonic counter. Consumers spin
//     (thread 0 only, s_sleep between polls) until 64*(t+1) arrivals.
//   - h[t] reads stay NORMAL cached loads: hs is time-indexed, each region
//     written exactly once (L2-bypassed) and read only after the barrier, so
//     no XCD L2 can hold a stale line -> no buffer_wbl2/buffer_inv needed.
//   - groups (bg) are independent: 4 separate 64-block barriers, no convoy.
// ---------------------------------------------------------------------------
__global__ __launch_bounds__(256, 1) void lstm_persistent(
    const unsigned short* __restrict__ Wfrag,
    const unsigned short* __restrict__ gates,   // frag layout, half bits
    __hip_bfloat16* __restrict__ hs,            // [S+1,B,H]
    unsigned int* __restrict__ arr)             // [4] per-bg arrival counters
{
    const int tid  = threadIdx.x;
    const int wid  = tid >> 6;            // wave = gate
    const int lane = tid & 63;
    const int ug = blockIdx.x;
    const int bg = blockIdx.y;
    const int n0 = ug * 16;
    const int fr = lane & 15, fq = lane >> 4;
    const int m0g = bg * 32;

    __shared__ alignas(16) unsigned short As[32][1048];  // h slab 32x1024
    __shared__ float Gs[32][65];                          // gate exchange

    // ---- W fragments: 32 coalesced 16B loads straight to registers, ONCE ----
    short8 bfr[32];
    {
        const unsigned short* wf =
            Wfrag + ((size_t)((ug * 4 + wid) * 32) * 64 + lane) * 8;
#pragma unroll
        for (int f = 0; f < 32; ++f)
            bfr[f] = *(const short8*)(wf + (size_t)f * 512);
    }

    // cell-state registers: this thread owns batch row m0g+cm2, units u0,u0+1
    const int cm2 = tid >> 3, up = tid & 7;
    const int u0 = 2 * up;
    float2 cc;
    cc.x = 0.f;
    cc.y = 0.f;

    // fused ih-gates base (per-lane, t-stride 524288)
    const unsigned short* gbase = gates
        + (size_t)(wid * 8 + (ug >> 3)) * 16384
        + (size_t)(ug & 7) * 2048 + fr * 128 + fq * 32 + bg * 8;

    const unsigned short* a0p = &As[fr][fq * 8];
    const unsigned short* a1p = &As[16 + fr][fq * 8];

    for (int t = 0; t < S_; ++t) {
        // ---- issue the fused ih-gate load early (consumed after MFMA) ----
        union { short8 v; __half h[8]; } gih;
        gih.v = *(const short8*)(gbase + (size_t)t * 524288);

        // ---- stage h_prev slab [32][1024] to LDS (normal cached loads) ----
        {
            const __hip_bfloat16* hprev =
                hs + (size_t)t * (B_ * H_) + (size_t)m0g * H_;
#pragma unroll
            for (int i = 0; i < 16; ++i) {
                const int e = i * 256 + tid;          // 16B-chunk id
                const int r = e >> 7, ch = (e & 127) * 8;
                *(short8*)&As[r][ch] = *(const short8*)(hprev + r * H_ + ch);
            }
        }
        __syncthreads();

        // ---- 64 MFMAs: full K=1024 ----
        f32x4 acc0 = {0.f, 0.f, 0.f, 0.f}, acc1 = {0.f, 0.f, 0.f, 0.f};
#pragma unroll
        for (int f = 0; f < 32; ++f) {
            short8 a0 = *(const short8*)(a0p + f * 32);
            short8 a1 = *(const short8*)(a1p + f * 32);
            acc0 = __builtin_amdgcn_mfma_f32_16x16x32_bf16(a0, bfr[f], acc0, 0, 0, 0);
            acc1 = __builtin_amdgcn_mfma_f32_16x16x32_bf16(a1, bfr[f], acc1, 0, 0, 0);
        }

        // fused add of precomputed ih-gates (+bias)
#pragma unroll
        for (int r = 0; r < 4; ++r) {
            acc0[r] += __half2float(gih.h[r]);
            acc1[r] += __half2float(gih.h[4 + r]);
        }

        // ---- exchange complete gates: Gs[m][gate*16+u] ----
        {
            const int col = wid * 16 + fr;
            const int rb = fq * 4;
#pragma unroll
            for (int r = 0; r < 4; ++r) {
                Gs[rb + r][col]      = acc0[r];
                Gs[16 + rb + r][col] = acc1[r];
            }
        }
        __syncthreads();

        // ---- cell update: reg-resident c, h tile -> hs[t+1] via LLC ----
        {
            float gi0 = Gs[cm2][u0],      gi1 = Gs[cm2][u0 + 1];
            float gf0 = Gs[cm2][16 + u0], gf1 = Gs[cm2][16 + u0 + 1];
            float gg0 = Gs[cm2][32 + u0], gg1 = Gs[cm2][32 + u0 + 1];
            float go0 = Gs[cm2][48 + u0], go1 = Gs[cm2][48 + u0 + 1];
            float si0 = 1.f / (1.f + __expf(-gi0));
            float sf0 = 1.f / (1.f + __expf(-gf0));
            float so0 = 1.f / (1.f + __expf(-go0));
            float si1 = 1.f / (1.f + __expf(-gi1));
            float sf1 = 1.f / (1.f + __expf(-gf1));
            float so1 = 1.f / (1.f + __expf(-go1));
            cc.x = sf0 * cc.x + si0 * tanhf(gg0);
            cc.y = sf1 * cc.y + si1 * tanhf(gg1);
            float h0 = so0 * tanhf(cc.x);
            float h1 = so1 * tanhf(cc.y);
            unsigned int hv =
                (unsigned int)(unsigned short)f2b(h0) |
                ((unsigned int)(unsigned short)f2b(h1) << 16);
            unsigned int* dst = (unsigned int*)
                (hs + (size_t)(t + 1) * (B_ * H_) +
                 (size_t)(m0g + cm2) * H_ + n0) + up;
            // agent-scope store: bypasses L1/L2, lands at coherent LLC
            __hip_atomic_store(dst, hv, __ATOMIC_RELAXED,
                               __HIP_MEMORY_SCOPE_AGENT);
        }

        if (t < S_ - 1) {
            // drain this wave's store to the coherence point
            asm volatile("s_waitcnt vmcnt(0)" ::: "memory");
            __syncthreads();   // all 4 waves' stores drained
            if (tid == 0) {
                __hip_atomic_fetch_add(arr + bg, 1u, __ATOMIC_RELAXED,
                                       __HIP_MEMORY_SCOPE_AGENT);
                const unsigned int target = 64u * (unsigned int)(t + 1);
                while (__hip_atomic_load(arr + bg, __ATOMIC_RELAXED,
                                         __HIP_MEMORY_SCOPE_AGENT) < target)
                    __builtin_amdgcn_s_sleep(1);
            }
            asm volatile("" ::: "memory");  // no loads hoisted above the spin
            __syncthreads();
        }
    }
}

// ---------------------------------------------------------------------------
// Head: one wave per (b,t): out = h . lin_W^T + lin_b, masked by lengths.
// ---------------------------------------------------------------------------
__global__ __launch_bounds__(256) void final_linear(
    const __hip_bfloat16* __restrict__ hs,
    const float* __restrict__ lin_W,
    const float* __restrict__ lin_b,
    const int* __restrict__ lengths,
    float* __restrict__ out)
{
    const int wid  = threadIdx.x >> 6;
    const int lane = threadIdx.x & 63;
    const int p = blockIdx.x * 4 + wid;
    const int b = p >> 7;
    const int t = p & 127;
    const __hip_bfloat16* h =
        hs + (size_t)(t + 1) * (B_ * H_) + (size_t)b * H_;
    float s0 = 0.f, s1 = 0.f;
#pragma unroll
    for (int i = 0; i < 16; ++i) {
        int n = lane + 64 * i;
        float hv = __bfloat162float(h[n]);
        s0 += hv * lin_W[n];
        s1 += hv * lin_W[H_ + n];
    }
#pragma unroll
    for (int off = 32; off > 0; off >>= 1) {
        s0 += __shfl_down(s0, off);
        s1 += __shfl_down(s1, off);
    }
    if (lane == 0) {
        float* o = out + (size_t)p * 2;
        if (t < lengths[b]) {
            o[0] = s0 + lin_b[0];
            o[1] = s1 + lin_b[1];
        } else {
            o[0] = 1.0f;
            o[1] = 0.0f;
        }
    }
}

extern "C" void kernel_launch(void* const* d_in, const int* in_sizes, int n_in,
                              void* d_out, int out_size, void* d_ws,
                              size_t ws_size, hipStream_t stream) {
    const int* x              = (const int*)d_in[0];
    const int* lengths        = (const int*)d_in[1];
    const float* embed_W      = (const float*)d_in[2];
    const float* W_ih         = (const float*)d_in[3];
    const float* W_hh         = (const float*)d_in[4];
    const float* b_ih         = (const float*)d_in[5];
    const float* b_hh         = (const float*)d_in[6];
    const float* lin_W        = (const float*)d_in[7];
    const float* lin_b        = (const float*)d_in[8];
    float* out                = (float*)d_out;

    // ws layout:
    //   hs bf16 [S+1,B,H]      @ 0            (33,816,576)
    //   gates half (frag)      @ 33,816,576   (134,217,728)
    //   bias fp32 [4096]       @ 168,034,304  (16,384)
    //   Wfrag bf16             @ 168,050,688  (8,388,608)
    //   arr u32 [4] barriers   @ 176,439,296  (64)
    //   xe bf16 [S,B,320]      @ hs+262,144   (10,485,760) [alias, consumed
    //   W_ihp bf16 [4096,320]  @ hs+10,747,904 (2,621,440)  before steps]
    char* ws = (char*)d_ws;
    __hip_bfloat16* hs    = (__hip_bfloat16*)(ws + 0);
    unsigned short* gates = (unsigned short*)(ws + 33816576);
    float* bias           = (float*)(ws + 168034304);
    unsigned short* Wfrag = (unsigned short*)(ws + 168050688);
    unsigned int* arr     = (unsigned int*)(ws + 176439296);
    unsigned short* xe    = (unsigned short*)(ws + 262144);
    unsigned short* Wp    = (unsigned short*)(ws + 10747904);

    prep_bias<<<16, 256, 0, stream>>>(b_ih, b_hh, bias);
    prep_wih<<<(4096 * IP_ + 255) / 256, 256, 0, stream>>>(W_ih, Wp);
    prep_xe<<<(S_ * B_ * IP_ + 255) / 256, 256, 0, stream>>>(x, embed_W, xe);
    prep_wfrag<<<2048, 256, 0, stream>>>(W_hh, Wfrag);
    (void)hipMemsetAsync(hs, 0, (size_t)B_ * H_ * sizeof(__hip_bfloat16), stream);
    (void)hipMemsetAsync(arr, 0, 64, stream);

    gemm_ih<<<dim3(32, 128), 256, 0, stream>>>(xe, Wp, bias, gates);

    // cooperative launch for the residency guarantee (grid.sync NOT used)
    {
        void* kargs[4];
        kargs[0] = (void*)&Wfrag;
        kargs[1] = (void*)&gates;
        kargs[2] = (void*)&hs;
        kargs[3] = (void*)&arr;
        (void)hipLaunchCooperativeKernel((const void*)lstm_persistent,
                                         dim3(64, 4), dim3(256, 1, 1),
                                         kargs, 0, stream);
    }

    final_linear<<<dim3((B_ * S_) / 4), 256, 0, stream>>>(
        hs, lin_W, lin_b, lengths, out);
}

// Round 4
// 1425.233 us; speedup vs baseline: 5.4180x; 1.1169x over previous
//
#include <hip/hip_runtime.h>
#include <hip/hip_bf16.h>
#include <hip/hip_fp16.h>

#define B_ 128
#define S_ 128
#define I_ 300
#define IP_ 320
#define H_ 1024
#define C_ 2

typedef __attribute__((ext_vector_type(8))) short short8;
typedef __attribute__((ext_vector_type(4))) float f32x4;

__device__ inline short f2b(float f) {
    union { __hip_bfloat16 h; unsigned short s; } cv;
    cv.h = __float2bfloat16(f);
    return (short)cv.s;
}

__global__ __launch_bounds__(256) void prep_bias(
    const float* __restrict__ b_ih, const float* __restrict__ b_hh,
    float* __restrict__ bias)
{
    int i = blockIdx.x * 256 + threadIdx.x;
    if (i < 4 * H_) bias[i] = b_ih[i] + b_hh[i];
}

// W_ihp bf16 [4096][320], zero-padded cols 300..319
__global__ __launch_bounds__(256) void prep_wih(
    const float* __restrict__ W_ih, unsigned short* __restrict__ Wp)
{
    int idx = blockIdx.x * 256 + threadIdx.x;
    if (idx >= 4096 * IP_) return;
    int row = idx / IP_, k = idx - row * IP_;
    Wp[idx] = (k < I_) ? (unsigned short)f2b(W_ih[row * I_ + k]) : 0;
}

// xe bf16 [S][B][320]: gathered embedding rows, zero-padded
__global__ __launch_bounds__(256) void prep_xe(
    const int* __restrict__ x, const float* __restrict__ embed_W,
    unsigned short* __restrict__ xe)
{
    int idx = blockIdx.x * 256 + threadIdx.x;
    if (idx >= S_ * B_ * IP_) return;
    int k = idx % IP_;
    int tb = idx / IP_;
    int b = tb % B_, t = tb / B_;
    int row = x[b * S_ + t];
    xe[idx] = (k < I_) ? (unsigned short)f2b(embed_W[(size_t)row * I_ + k]) : 0;
}

// Wfrag: W_hh in per-lane MFMA B-fragment order (R6/R7-proven layout)
__global__ __launch_bounds__(256) void prep_wfrag(
    const float* __restrict__ W_hh, unsigned short* __restrict__ Wfrag)
{
    int idx = blockIdx.x * 256 + threadIdx.x;   // 0 .. 524287
    const int lane = idx & 63;
    const int f    = (idx >> 6) & 31;
    const int wid  = (idx >> 11) & 3;
    const int ug   = idx >> 13;
    const int row  = wid * H_ + ug * 16 + (lane & 15);
    const int k0   = f * 32 + (lane >> 4) * 8;
    const float* src = W_hh + (size_t)row * H_ + k0;
    unsigned short* dst = Wfrag + (size_t)idx * 8;
#pragma unroll
    for (int j = 0; j < 8; ++j)
        dst[j] = (unsigned short)f2b(src[j]);
}

// ---------------------------------------------------------------------------
// gates in FRAGMENT layout (half bits):
//   idx = t*524288 + bx*16384 + nt*2048 + fr*128 + fq*32 + wp*8 + mt*4 + r
//   holds gate for col n = bx*128+nt*16+fr, batch m = wp*32+mt*16+fq*4+r.
// ---------------------------------------------------------------------------
__global__ __launch_bounds__(256) void gemm_ih(
    const unsigned short* __restrict__ xe,   // [S][B][320] bf16
    const unsigned short* __restrict__ Wp,   // [4096][320] bf16
    const float* __restrict__ bias,          // [4096]
    unsigned short* __restrict__ gates)      // frag layout, half bits
{
    const int tid = threadIdx.x;
    const int wid = tid >> 6, lane = tid & 63;
    const int fr = lane & 15, fq = lane >> 4;
    const int bx = blockIdx.x;            // n-tile base bx*128
    const int t  = blockIdx.y;

    __shared__ alignas(16) unsigned short As_[128][40];
    __shared__ alignas(16) unsigned short Bs_[128][40];

    const int sr = tid >> 1;
    const int sc = (tid & 1) * 16;
    const unsigned short* arow = xe + ((size_t)t * B_ + sr) * IP_;
    const unsigned short* brow = Wp + (size_t)(bx * 128 + sr) * IP_;

    f32x4 acc[2][8] = {};

    for (int kc = 0; kc < 10; ++kc) {
        __syncthreads();
        const int k0 = kc * 32 + sc;
        *(short8*)&As_[sr][sc]     = *(const short8*)(arow + k0);
        *(short8*)&As_[sr][sc + 8] = *(const short8*)(arow + k0 + 8);
        *(short8*)&Bs_[sr][sc]     = *(const short8*)(brow + k0);
        *(short8*)&Bs_[sr][sc + 8] = *(const short8*)(brow + k0 + 8);
        __syncthreads();
        short8 bfrag[8];
#pragma unroll
        for (int nt = 0; nt < 8; ++nt)
            bfrag[nt] = *(const short8*)&Bs_[nt * 16 + fr][fq * 8];
#pragma unroll
        for (int mt = 0; mt < 2; ++mt) {
            short8 a = *(const short8*)&As_[wid * 32 + mt * 16 + fr][fq * 8];
#pragma unroll
            for (int nt = 0; nt < 8; ++nt)
                acc[mt][nt] = __builtin_amdgcn_mfma_f32_16x16x32_bf16(
                    a, bfrag[nt], acc[mt][nt], 0, 0, 0);
        }
    }
    // epilogue: one coalesced 16-B store per nt
    unsigned short* gbase = gates + (size_t)t * 524288 + (size_t)bx * 16384
                          + fr * 128 + fq * 32 + wid * 8;
#pragma unroll
    for (int nt = 0; nt < 8; ++nt) {
        const float bs = bias[bx * 128 + nt * 16 + fr];
        short8 pk;
#pragma unroll
        for (int r = 0; r < 4; ++r) {
            pk[r]     = (short)__half_as_ushort(__float2half(acc[0][nt][r] + bs));
            pk[4 + r] = (short)__half_as_ushort(__float2half(acc[1][nt][r] + bs));
        }
        *(short8*)(gbase + nt * 2048) = pk;
    }
}

// ---------------------------------------------------------------------------
// Persistent recurrent kernel, v3 barrier: per-block FLAG ARRAY (no RMW).
//   grid (64 ug, 4 bg) = 256 blocks, 256 thr = 4 waves; wave = gate.
//   - W fragments (bfr[32], 128 VGPR) loaded ONCE for all steps
//   - c state in registers; no c_state global traffic
//   - h[t+1] stored with relaxed AGENT-scope atomic stores (L1/L2-bypassing,
//     land at coherent LLC), drained with vmcnt(0).
//   - barrier arrive = ONE plain agent-scope flag store arr[bg*64+ug] = t+1
//     (monotonic, no reset, no atomic RMW -> no LLC hot-line serialization).
//   - barrier wait = wave 0's 64 lanes each poll one flag (4 cachelines,
//     parallel read-shared loads) until __all(flag >= t+1).
//   - gih gate fragment for step t+1 prefetched BEFORE the barrier so its
//     HBM latency hides under store-drain + barrier.
// ---------------------------------------------------------------------------
__global__ __launch_bounds__(256, 1) void lstm_persistent(
    const unsigned short* __restrict__ Wfrag,
    const unsigned short* __restrict__ gates,   // frag layout, half bits
    __hip_bfloat16* __restrict__ hs,            // [S+1,B,H]
    unsigned int* __restrict__ arr)             // [4][64] per-block step flags
{
    const int tid  = threadIdx.x;
    const int wid  = tid >> 6;            // wave = gate
    const int lane = tid & 63;
    const int ug = blockIdx.x;
    const int bg = blockIdx.y;
    const int n0 = ug * 16;
    const int fr = lane & 15, fq = lane >> 4;
    const int m0g = bg * 32;

    __shared__ alignas(16) unsigned short As[32][1048];  // h slab 32x1024
    __shared__ float Gs[32][65];                          // gate exchange

    // ---- W fragments: 32 coalesced 16B loads straight to registers, ONCE ----
    short8 bfr[32];
    {
        const unsigned short* wf =
            Wfrag + ((size_t)((ug * 4 + wid) * 32) * 64 + lane) * 8;
#pragma unroll
        for (int f = 0; f < 32; ++f)
            bfr[f] = *(const short8*)(wf + (size_t)f * 512);
    }

    // cell-state registers: this thread owns batch row m0g+cm2, units u0,u0+1
    const int cm2 = tid >> 3, up = tid & 7;
    const int u0 = 2 * up;
    float2 cc;
    cc.x = 0.f;
    cc.y = 0.f;

    // fused ih-gates base (per-lane, t-stride 524288)
    const unsigned short* gbase = gates
        + (size_t)(wid * 8 + (ug >> 3)) * 16384
        + (size_t)(ug & 7) * 2048 + fr * 128 + fq * 32 + bg * 8;

    const unsigned short* a0p = &As[fr][fq * 8];
    const unsigned short* a1p = &As[16 + fr][fq * 8];

    unsigned int* my_flag   = arr + bg * 64 + ug;
    unsigned int* poll_flag = arr + bg * 64 + lane;

    union GU { short8 v; __half h[8]; };
    GU gcur, gnxt;
    gcur.v = *(const short8*)gbase;           // t = 0 gates

    for (int t = 0; t < S_; ++t) {
        // ---- stage h_prev slab [32][1024] to LDS (normal cached loads) ----
        {
            const __hip_bfloat16* hprev =
                hs + (size_t)t * (B_ * H_) + (size_t)m0g * H_;
#pragma unroll
            for (int i = 0; i < 16; ++i) {
                const int e = i * 256 + tid;          // 16B-chunk id
                const int r = e >> 7, ch = (e & 127) * 8;
                *(short8*)&As[r][ch] = *(const short8*)(hprev + r * H_ + ch);
            }
        }
        __syncthreads();

        // ---- 64 MFMAs: full K=1024 ----
        f32x4 acc0 = {0.f, 0.f, 0.f, 0.f}, acc1 = {0.f, 0.f, 0.f, 0.f};
#pragma unroll
        for (int f = 0; f < 32; ++f) {
            short8 a0 = *(const short8*)(a0p + f * 32);
            short8 a1 = *(const short8*)(a1p + f * 32);
            acc0 = __builtin_amdgcn_mfma_f32_16x16x32_bf16(a0, bfr[f], acc0, 0, 0, 0);
            acc1 = __builtin_amdgcn_mfma_f32_16x16x32_bf16(a1, bfr[f], acc1, 0, 0, 0);
        }

        // fused add of precomputed ih-gates (+bias)
#pragma unroll
        for (int r = 0; r < 4; ++r) {
            acc0[r] += __half2float(gcur.h[r]);
            acc1[r] += __half2float(gcur.h[4 + r]);
        }

        // ---- exchange complete gates: Gs[m][gate*16+u] ----
        {
            const int col = wid * 16 + fr;
            const int rb = fq * 4;
#pragma unroll
            for (int r = 0; r < 4; ++r) {
                Gs[rb + r][col]      = acc0[r];
                Gs[16 + rb + r][col] = acc1[r];
            }
        }

        // ---- prefetch next step's gates: latency hides under drain+barrier
        if (t + 1 < S_)
            gnxt.v = *(const short8*)(gbase + (size_t)(t + 1) * 524288);

        __syncthreads();

        // ---- cell update: reg-resident c, h tile -> hs[t+1] via LLC ----
        {
            float gi0 = Gs[cm2][u0],      gi1 = Gs[cm2][u0 + 1];
            float gf0 = Gs[cm2][16 + u0], gf1 = Gs[cm2][16 + u0 + 1];
            float gg0 = Gs[cm2][32 + u0], gg1 = Gs[cm2][32 + u0 + 1];
            float go0 = Gs[cm2][48 + u0], go1 = Gs[cm2][48 + u0 + 1];
            float si0 = 1.f / (1.f + __expf(-gi0));
            float sf0 = 1.f / (1.f + __expf(-gf0));
            float so0 = 1.f / (1.f + __expf(-go0));
            float si1 = 1.f / (1.f + __expf(-gi1));
            float sf1 = 1.f / (1.f + __expf(-gf1));
            float so1 = 1.f / (1.f + __expf(-go1));
            cc.x = sf0 * cc.x + si0 * tanhf(gg0);
            cc.y = sf1 * cc.y + si1 * tanhf(gg1);
            float h0 = so0 * tanhf(cc.x);
            float h1 = so1 * tanhf(cc.y);
            unsigned int hv =
                (unsigned int)(unsigned short)f2b(h0) |
                ((unsigned int)(unsigned short)f2b(h1) << 16);
            unsigned int* dst = (unsigned int*)
                (hs + (size_t)(t + 1) * (B_ * H_) +
                 (size_t)(m0g + cm2) * H_ + n0) + up;
            // agent-scope store: bypasses L1/L2, lands at coherent LLC
            __hip_atomic_store(dst, hv, __ATOMIC_RELAXED,
                               __HIP_MEMORY_SCOPE_AGENT);
        }

        if (t < S_ - 1) {
            // drain this wave's h stores (and gih prefetch) to coherence point
            asm volatile("s_waitcnt vmcnt(0)" ::: "memory");
            __syncthreads();   // all 4 waves' stores drained
            if (wid == 0) {
                if (lane == 0)
                    __hip_atomic_store(my_flag, (unsigned int)(t + 1),
                                       __ATOMIC_RELAXED,
                                       __HIP_MEMORY_SCOPE_AGENT);
                const unsigned int tgt = (unsigned int)(t + 1);
                for (;;) {
                    unsigned int v = __hip_atomic_load(
                        poll_flag, __ATOMIC_RELAXED, __HIP_MEMORY_SCOPE_AGENT);
                    if (__all((int)(v >= tgt))) break;
                    __builtin_amdgcn_s_sleep(2);
                }
            }
            asm volatile("" ::: "memory");  // no loads hoisted above the spin
            __syncthreads();
        }
        gcur = gnxt;
    }
}

// ---------------------------------------------------------------------------
// Head: one wave per (b,t): out = h . lin_W^T + lin_b, masked by lengths.
// ---------------------------------------------------------------------------
__global__ __launch_bounds__(256) void final_linear(
    const __hip_bfloat16* __restrict__ hs,
    const float* __restrict__ lin_W,
    const float* __restrict__ lin_b,
    const int* __restrict__ lengths,
    float* __restrict__ out)
{
    const int wid  = threadIdx.x >> 6;
    const int lane = threadIdx.x & 63;
    const int p = blockIdx.x * 4 + wid;
    const int b = p >> 7;
    const int t = p & 127;
    const __hip_bfloat16* h =
        hs + (size_t)(t + 1) * (B_ * H_) + (size_t)b * H_;
    float s0 = 0.f, s1 = 0.f;
#pragma unroll
    for (int i = 0; i < 16; ++i) {
        int n = lane + 64 * i;
        float hv = __bfloat162float(h[n]);
        s0 += hv * lin_W[n];
        s1 += hv * lin_W[H_ + n];
    }
#pragma unroll
    for (int off = 32; off > 0; off >>= 1) {
        s0 += __shfl_down(s0, off);
        s1 += __shfl_down(s1, off);
    }
    if (lane == 0) {
        float* o = out + (size_t)p * 2;
        if (t < lengths[b]) {
            o[0] = s0 + lin_b[0];
            o[1] = s1 + lin_b[1];
        } else {
            o[0] = 1.0f;
            o[1] = 0.0f;
        }
    }
}

extern "C" void kernel_launch(void* const* d_in, const int* in_sizes, int n_in,
                              void* d_out, int out_size, void* d_ws,
                              size_t ws_size, hipStream_t stream) {
    const int* x              = (const int*)d_in[0];
    const int* lengths        = (const int*)d_in[1];
    const float* embed_W      = (const float*)d_in[2];
    const float* W_ih         = (const float*)d_in[3];
    const float* W_hh         = (const float*)d_in[4];
    const float* b_ih         = (const float*)d_in[5];
    const float* b_hh         = (const float*)d_in[6];
    const float* lin_W        = (const float*)d_in[7];
    const float* lin_b        = (const float*)d_in[8];
    float* out                = (float*)d_out;

    // ws layout:
    //   hs bf16 [S+1,B,H]      @ 0            (33,816,576)
    //   gates half (frag)      @ 33,816,576   (134,217,728)
    //   bias fp32 [4096]       @ 168,034,304  (16,384)
    //   Wfrag bf16             @ 168,050,688  (8,388,608)
    //   arr u32 [4][64] flags  @ 176,439,296  (1,024)
    //   xe bf16 [S,B,320]      @ hs+262,144   (10,485,760) [alias, consumed
    //   W_ihp bf16 [4096,320]  @ hs+10,747,904 (2,621,440)  before steps]
    char* ws = (char*)d_ws;
    __hip_bfloat16* hs    = (__hip_bfloat16*)(ws + 0);
    unsigned short* gates = (unsigned short*)(ws + 33816576);
    float* bias           = (float*)(ws + 168034304);
    unsigned short* Wfrag = (unsigned short*)(ws + 168050688);
    unsigned int* arr     = (unsigned int*)(ws + 176439296);
    unsigned short* xe    = (unsigned short*)(ws + 262144);
    unsigned short* Wp    = (unsigned short*)(ws + 10747904);

    prep_bias<<<16, 256, 0, stream>>>(b_ih, b_hh, bias);
    prep_wih<<<(4096 * IP_ + 255) / 256, 256, 0, stream>>>(W_ih, Wp);
    prep_xe<<<(S_ * B_ * IP_ + 255) / 256, 256, 0, stream>>>(x, embed_W, xe);
    prep_wfrag<<<2048, 256, 0, stream>>>(W_hh, Wfrag);
    (void)hipMemsetAsync(hs, 0, (size_t)B_ * H_ * sizeof(__hip_bfloat16), stream);
    (void)hipMemsetAsync(arr, 0, 1024, stream);

    gemm_ih<<<dim3(32, 128), 256, 0, stream>>>(xe, Wp, bias, gates);

    // cooperative launch for the residency guarantee (grid.sync NOT used)
    {
        void* kargs[4];
        kargs[0] = (void*)&Wfrag;
        kargs[1] = (void*)&gates;
        kargs[2] = (void*)&hs;
        kargs[3] = (void*)&arr;
        (void)hipLaunchCooperativeKernel((const void*)lstm_persistent,
                                         dim3(64, 4), dim3(256, 1, 1),
                                         kargs, 0, stream);
    }

    final_linear<<<dim3((B_ * S_) / 4), 256, 0, stream>>>(
        hs, lin_W, lin_b, lengths, out);
}

// Round 5
// 1212.040 us; speedup vs baseline: 6.3710x; 1.1759x over previous
//
#include <hip/hip_runtime.h>
#include <hip/hip_bf16.h>
#include <hip/hip_fp16.h>

#define B_ 128
#define S_ 128
#define I_ 300
#define IP_ 320
#define H_ 1024
#define C_ 2

typedef __attribute__((ext_vector_type(8))) short short8;
typedef __attribute__((ext_vector_type(4))) float f32x4;

__device__ inline short f2b(float f) {
    union { __hip_bfloat16 h; unsigned short s; } cv;
    cv.h = __float2bfloat16(f);
    return (short)cv.s;
}

__global__ __launch_bounds__(256) void prep_bias(
    const float* __restrict__ b_ih, const float* __restrict__ b_hh,
    float* __restrict__ bias)
{
    int i = blockIdx.x * 256 + threadIdx.x;
    if (i < 4 * H_) bias[i] = b_ih[i] + b_hh[i];
}

// W_ihp bf16 [4096][320], zero-padded cols 300..319
__global__ __launch_bounds__(256) void prep_wih(
    const float* __restrict__ W_ih, unsigned short* __restrict__ Wp)
{
    int idx = blockIdx.x * 256 + threadIdx.x;
    if (idx >= 4096 * IP_) return;
    int row = idx / IP_, k = idx - row * IP_;
    Wp[idx] = (k < I_) ? (unsigned short)f2b(W_ih[row * I_ + k]) : 0;
}

// xe bf16 [S][B][320]: gathered embedding rows, zero-padded
__global__ __launch_bounds__(256) void prep_xe(
    const int* __restrict__ x, const float* __restrict__ embed_W,
    unsigned short* __restrict__ xe)
{
    int idx = blockIdx.x * 256 + threadIdx.x;
    if (idx >= S_ * B_ * IP_) return;
    int k = idx % IP_;
    int tb = idx / IP_;
    int b = tb % B_, t = tb / B_;
    int row = x[b * S_ + t];
    xe[idx] = (k < I_) ? (unsigned short)f2b(embed_W[(size_t)row * I_ + k]) : 0;
}

// Wfrag: W_hh in per-lane MFMA B-fragment order (R6/R7-proven layout)
__global__ __launch_bounds__(256) void prep_wfrag(
    const float* __restrict__ W_hh, unsigned short* __restrict__ Wfrag)
{
    int idx = blockIdx.x * 256 + threadIdx.x;   // 0 .. 524287
    const int lane = idx & 63;
    const int f    = (idx >> 6) & 31;
    const int wid  = (idx >> 11) & 3;
    const int ug   = idx >> 13;
    const int row  = wid * H_ + ug * 16 + (lane & 15);
    const int k0   = f * 32 + (lane >> 4) * 8;
    const float* src = W_hh + (size_t)row * H_ + k0;
    unsigned short* dst = Wfrag + (size_t)idx * 8;
#pragma unroll
    for (int j = 0; j < 8; ++j)
        dst[j] = (unsigned short)f2b(src[j]);
}

// ---------------------------------------------------------------------------
// gates in FRAGMENT layout (half bits):
//   idx = t*524288 + bx*16384 + nt*2048 + fr*128 + fq*32 + wp*8 + mt*4 + r
//   holds gate for col n = bx*128+nt*16+fr, batch m = wp*32+mt*16+fq*4+r.
// ---------------------------------------------------------------------------
__global__ __launch_bounds__(256) void gemm_ih(
    const unsigned short* __restrict__ xe,   // [S][B][320] bf16
    const unsigned short* __restrict__ Wp,   // [4096][320] bf16
    const float* __restrict__ bias,          // [4096]
    unsigned short* __restrict__ gates)      // frag layout, half bits
{
    const int tid = threadIdx.x;
    const int wid = tid >> 6, lane = tid & 63;
    const int fr = lane & 15, fq = lane >> 4;
    const int bx = blockIdx.x;            // n-tile base bx*128
    const int t  = blockIdx.y;

    __shared__ alignas(16) unsigned short As_[128][40];
    __shared__ alignas(16) unsigned short Bs_[128][40];

    const int sr = tid >> 1;
    const int sc = (tid & 1) * 16;
    const unsigned short* arow = xe + ((size_t)t * B_ + sr) * IP_;
    const unsigned short* brow = Wp + (size_t)(bx * 128 + sr) * IP_;

    f32x4 acc[2][8] = {};

    for (int kc = 0; kc < 10; ++kc) {
        __syncthreads();
        const int k0 = kc * 32 + sc;
        *(short8*)&As_[sr][sc]     = *(const short8*)(arow + k0);
        *(short8*)&As_[sr][sc + 8] = *(const short8*)(arow + k0 + 8);
        *(short8*)&Bs_[sr][sc]     = *(const short8*)(brow + k0);
        *(short8*)&Bs_[sr][sc + 8] = *(const short8*)(brow + k0 + 8);
        __syncthreads();
        short8 bfrag[8];
#pragma unroll
        for (int nt = 0; nt < 8; ++nt)
            bfrag[nt] = *(const short8*)&Bs_[nt * 16 + fr][fq * 8];
#pragma unroll
        for (int mt = 0; mt < 2; ++mt) {
            short8 a = *(const short8*)&As_[wid * 32 + mt * 16 + fr][fq * 8];
#pragma unroll
            for (int nt = 0; nt < 8; ++nt)
                acc[mt][nt] = __builtin_amdgcn_mfma_f32_16x16x32_bf16(
                    a, bfrag[nt], acc[mt][nt], 0, 0, 0);
        }
    }
    // epilogue: one coalesced 16-B store per nt
    unsigned short* gbase = gates + (size_t)t * 524288 + (size_t)bx * 16384
                          + fr * 128 + fq * 32 + wid * 8;
#pragma unroll
    for (int nt = 0; nt < 8; ++nt) {
        const float bs = bias[bx * 128 + nt * 16 + fr];
        short8 pk;
#pragma unroll
        for (int r = 0; r < 4; ++r) {
            pk[r]     = (short)__half_as_ushort(__float2half(acc[0][nt][r] + bs));
            pk[4 + r] = (short)__half_as_ushort(__float2half(acc[1][nt][r] + bs));
        }
        *(short8*)(gbase + nt * 2048) = pk;
    }
}

// ---------------------------------------------------------------------------
// Persistent recurrent kernel, v4 barrier: 3-hop hierarchical, every LLC
// line has exactly ONE reader (kills uncached same-line poll contention).
//   grid (64 ug, 4 bg) = 256 blocks, 256 thr = 4 waves; wave = gate.
//   - W fragments (bfr[32], 128 VGPR) loaded ONCE for all steps
//   - c state in registers; no c_state global traffic
//   - h[t+1] stored with relaxed AGENT-scope atomic stores (LLC-direct),
//     drained with vmcnt(0).
//   - arrive: arr[bg][ug] = t+1 (packed 4 lines; 64 writers, 1 reader)
//   - detect: LEADER block (ug==0) wave 0 polls the 64 packed flags
//     (sole reader of those lines).
//   - broadcast: leader's 64 lanes store t+1 into 64 PRIVATE 64B-strided
//     lines; each follower polls only ITS OWN line (all lanes same addr ->
//     one merged request; sole reader per line).
//   - flags monotonic (no reset race); all 256 blocks co-resident
//     (cooperative launch).
//   - gih gate fragment for step t+1 prefetched BEFORE the barrier.
// ---------------------------------------------------------------------------
__global__ __launch_bounds__(256, 1) void lstm_persistent(
    const unsigned short* __restrict__ Wfrag,
    const unsigned short* __restrict__ gates,   // frag layout, half bits
    __hip_bfloat16* __restrict__ hs,            // [S+1,B,H]
    unsigned int* __restrict__ arr)             // arrivals[4][64] + epoch lines
{
    const int tid  = threadIdx.x;
    const int wid  = tid >> 6;            // wave = gate
    const int lane = tid & 63;
    const int ug = blockIdx.x;
    const int bg = blockIdx.y;
    const int n0 = ug * 16;
    const int fr = lane & 15, fq = lane >> 4;
    const int m0g = bg * 32;

    __shared__ alignas(16) unsigned short As[32][1048];  // h slab 32x1024
    __shared__ float Gs[32][65];                          // gate exchange

    // ---- W fragments: 32 coalesced 16B loads straight to registers, ONCE ----
    short8 bfr[32];
    {
        const unsigned short* wf =
            Wfrag + ((size_t)((ug * 4 + wid) * 32) * 64 + lane) * 8;
#pragma unroll
        for (int f = 0; f < 32; ++f)
            bfr[f] = *(const short8*)(wf + (size_t)f * 512);
    }

    // cell-state registers: this thread owns batch row m0g+cm2, units u0,u0+1
    const int cm2 = tid >> 3, up = tid & 7;
    const int u0 = 2 * up;
    float2 cc;
    cc.x = 0.f;
    cc.y = 0.f;

    // fused ih-gates base (per-lane, t-stride 524288)
    const unsigned short* gbase = gates
        + (size_t)(wid * 8 + (ug >> 3)) * 16384
        + (size_t)(ug & 7) * 2048 + fr * 128 + fq * 32 + bg * 8;

    const unsigned short* a0p = &As[fr][fq * 8];
    const unsigned short* a1p = &As[16 + fr][fq * 8];

    // barrier pointers (arr: [4][64] packed arrivals; epoch @ +4096 B:
    // [4][64] lines of 64 B each)
    unsigned int* my_flag   = arr + bg * 64 + ug;              // arrive
    unsigned int* poll_flag = arr + bg * 64 + lane;            // leader read
    unsigned int* epoch_st  = arr + 1024 + bg * 1024 + lane * 16; // leader bcast
    unsigned int* epoch_ld  = arr + 1024 + bg * 1024 + ug * 16;   // follower read

    union GU { short8 v; __half h[8]; };
    GU gcur, gnxt;
    gcur.v = *(const short8*)gbase;           // t = 0 gates

    for (int t = 0; t < S_; ++t) {
        // ---- stage h_prev slab [32][1024] to LDS (normal cached loads) ----
        {
            const __hip_bfloat16* hprev =
                hs + (size_t)t * (B_ * H_) + (size_t)m0g * H_;
#pragma unroll
            for (int i = 0; i < 16; ++i) {
                const int e = i * 256 + tid;          // 16B-chunk id
                const int r = e >> 7, ch = (e & 127) * 8;
                *(short8*)&As[r][ch] = *(const short8*)(hprev + r * H_ + ch);
            }
        }
        __syncthreads();

        // ---- 64 MFMAs: full K=1024 ----
        f32x4 acc0 = {0.f, 0.f, 0.f, 0.f}, acc1 = {0.f, 0.f, 0.f, 0.f};
#pragma unroll
        for (int f = 0; f < 32; ++f) {
            short8 a0 = *(const short8*)(a0p + f * 32);
            short8 a1 = *(const short8*)(a1p + f * 32);
            acc0 = __builtin_amdgcn_mfma_f32_16x16x32_bf16(a0, bfr[f], acc0, 0, 0, 0);
            acc1 = __builtin_amdgcn_mfma_f32_16x16x32_bf16(a1, bfr[f], acc1, 0, 0, 0);
        }

        // fused add of precomputed ih-gates (+bias)
#pragma unroll
        for (int r = 0; r < 4; ++r) {
            acc0[r] += __half2float(gcur.h[r]);
            acc1[r] += __half2float(gcur.h[4 + r]);
        }

        // ---- exchange complete gates: Gs[m][gate*16+u] ----
        {
            const int col = wid * 16 + fr;
            const int rb = fq * 4;
#pragma unroll
            for (int r = 0; r < 4; ++r) {
                Gs[rb + r][col]      = acc0[r];
                Gs[16 + rb + r][col] = acc1[r];
            }
        }

        // ---- prefetch next step's gates: latency hides under drain+barrier
        if (t + 1 < S_)
            gnxt.v = *(const short8*)(gbase + (size_t)(t + 1) * 524288);

        __syncthreads();

        // ---- cell update: reg-resident c, h tile -> hs[t+1] via LLC ----
        {
            float gi0 = Gs[cm2][u0],      gi1 = Gs[cm2][u0 + 1];
            float gf0 = Gs[cm2][16 + u0], gf1 = Gs[cm2][16 + u0 + 1];
            float gg0 = Gs[cm2][32 + u0], gg1 = Gs[cm2][32 + u0 + 1];
            float go0 = Gs[cm2][48 + u0], go1 = Gs[cm2][48 + u0 + 1];
            float si0 = 1.f / (1.f + __expf(-gi0));
            float sf0 = 1.f / (1.f + __expf(-gf0));
            float so0 = 1.f / (1.f + __expf(-go0));
            float si1 = 1.f / (1.f + __expf(-gi1));
            float sf1 = 1.f / (1.f + __expf(-gf1));
            float so1 = 1.f / (1.f + __expf(-go1));
            cc.x = sf0 * cc.x + si0 * tanhf(gg0);
            cc.y = sf1 * cc.y + si1 * tanhf(gg1);
            float h0 = so0 * tanhf(cc.x);
            float h1 = so1 * tanhf(cc.y);
            unsigned int hv =
                (unsigned int)(unsigned short)f2b(h0) |
                ((unsigned int)(unsigned short)f2b(h1) << 16);
            unsigned int* dst = (unsigned int*)
                (hs + (size_t)(t + 1) * (B_ * H_) +
                 (size_t)(m0g + cm2) * H_ + n0) + up;
            // agent-scope store: bypasses L1/L2, lands at coherent LLC
            __hip_atomic_store(dst, hv, __ATOMIC_RELAXED,
                               __HIP_MEMORY_SCOPE_AGENT);
        }

        if (t < S_ - 1) {
            // drain this wave's h stores (and gih prefetch) to coherence point
            asm volatile("s_waitcnt vmcnt(0)" ::: "memory");
            __syncthreads();   // all 4 waves' stores drained
            if (wid == 0) {
                const unsigned int tgt = (unsigned int)(t + 1);
                if (lane == 0)
                    __hip_atomic_store(my_flag, tgt, __ATOMIC_RELAXED,
                                       __HIP_MEMORY_SCOPE_AGENT);
                if (ug == 0) {
                    // leader: sole reader of the 64 packed arrival flags
                    for (;;) {
                        unsigned int v = __hip_atomic_load(
                            poll_flag, __ATOMIC_RELAXED,
                            __HIP_MEMORY_SCOPE_AGENT);
                        if (__all((int)(v >= tgt))) break;
                        __builtin_amdgcn_s_sleep(1);
                    }
                    // broadcast: one private 64B line per follower block
                    __hip_atomic_store(epoch_st, tgt, __ATOMIC_RELAXED,
                                       __HIP_MEMORY_SCOPE_AGENT);
                } else {
                    // follower: poll own private line (sole reader; all
                    // lanes load the same address -> one merged request)
                    for (;;) {
                        unsigned int v = __hip_atomic_load(
                            epoch_ld, __ATOMIC_RELAXED,
                            __HIP_MEMORY_SCOPE_AGENT);
                        if (__all((int)(v >= tgt))) break;
                        __builtin_amdgcn_s_sleep(1);
                    }
                }
            }
            asm volatile("" ::: "memory");  // no loads hoisted above the spin
            __syncthreads();
        }
        gcur = gnxt;
    }
}

// ---------------------------------------------------------------------------
// Head: one wave per (b,t): out = h . lin_W^T + lin_b, masked by lengths.
// ---------------------------------------------------------------------------
__global__ __launch_bounds__(256) void final_linear(
    const __hip_bfloat16* __restrict__ hs,
    const float* __restrict__ lin_W,
    const float* __restrict__ lin_b,
    const int* __restrict__ lengths,
    float* __restrict__ out)
{
    const int wid  = threadIdx.x >> 6;
    const int lane = threadIdx.x & 63;
    const int p = blockIdx.x * 4 + wid;
    const int b = p >> 7;
    const int t = p & 127;
    const __hip_bfloat16* h =
        hs + (size_t)(t + 1) * (B_ * H_) + (size_t)b * H_;
    float s0 = 0.f, s1 = 0.f;
#pragma unroll
    for (int i = 0; i < 16; ++i) {
        int n = lane + 64 * i;
        float hv = __bfloat162float(h[n]);
        s0 += hv * lin_W[n];
        s1 += hv * lin_W[H_ + n];
    }
#pragma unroll
    for (int off = 32; off > 0; off >>= 1) {
        s0 += __shfl_down(s0, off);
        s1 += __shfl_down(s1, off);
    }
    if (lane == 0) {
        float* o = out + (size_t)p * 2;
        if (t < lengths[b]) {
            o[0] = s0 + lin_b[0];
            o[1] = s1 + lin_b[1];
        } else {
            o[0] = 1.0f;
            o[1] = 0.0f;
        }
    }
}

extern "C" void kernel_launch(void* const* d_in, const int* in_sizes, int n_in,
                              void* d_out, int out_size, void* d_ws,
                              size_t ws_size, hipStream_t stream) {
    const int* x              = (const int*)d_in[0];
    const int* lengths        = (const int*)d_in[1];
    const float* embed_W      = (const float*)d_in[2];
    const float* W_ih         = (const float*)d_in[3];
    const float* W_hh         = (const float*)d_in[4];
    const float* b_ih         = (const float*)d_in[5];
    const float* b_hh         = (const float*)d_in[6];
    const float* lin_W        = (const float*)d_in[7];
    const float* lin_b        = (const float*)d_in[8];
    float* out                = (float*)d_out;

    // ws layout:
    //   hs bf16 [S+1,B,H]      @ 0            (33,816,576)
    //   gates half (frag)      @ 33,816,576   (134,217,728)
    //   bias fp32 [4096]       @ 168,034,304  (16,384)
    //   Wfrag bf16             @ 168,050,688  (8,388,608)
    //   barrier region         @ 176,439,296  (20,480: arrivals 4KB + epoch 16KB)
    //   xe bf16 [S,B,320]      @ hs+262,144   (10,485,760) [alias, consumed
    //   W_ihp bf16 [4096,320]  @ hs+10,747,904 (2,621,440)  before steps]
    char* ws = (char*)d_ws;
    __hip_bfloat16* hs    = (__hip_bfloat16*)(ws + 0);
    unsigned short* gates = (unsigned short*)(ws + 33816576);
    float* bias           = (float*)(ws + 168034304);
    unsigned short* Wfrag = (unsigned short*)(ws + 168050688);
    unsigned int* arr     = (unsigned int*)(ws + 176439296);
    unsigned short* xe    = (unsigned short*)(ws + 262144);
    unsigned short* Wp    = (unsigned short*)(ws + 10747904);

    prep_bias<<<16, 256, 0, stream>>>(b_ih, b_hh, bias);
    prep_wih<<<(4096 * IP_ + 255) / 256, 256, 0, stream>>>(W_ih, Wp);
    prep_xe<<<(S_ * B_ * IP_ + 255) / 256, 256, 0, stream>>>(x, embed_W, xe);
    prep_wfrag<<<2048, 256, 0, stream>>>(W_hh, Wfrag);
    (void)hipMemsetAsync(hs, 0, (size_t)B_ * H_ * sizeof(__hip_bfloat16), stream);
    (void)hipMemsetAsync(arr, 0, 20480, stream);

    gemm_ih<<<dim3(32, 128), 256, 0, stream>>>(xe, Wp, bias, gates);

    // cooperative launch for the residency guarantee (grid.sync NOT used)
    {
        void* kargs[4];
        kargs[0] = (void*)&Wfrag;
        kargs[1] = (void*)&gates;
        kargs[2] = (void*)&hs;
        kargs[3] = (void*)&arr;
        (void)hipLaunchCooperativeKernel((const void*)lstm_persistent,
                                         dim3(64, 4), dim3(256, 1, 1),
                                         kargs, 0, stream);
    }

    final_linear<<<dim3((B_ * S_) / 4), 256, 0, stream>>>(
        hs, lin_W, lin_b, lengths, out);
}

// Round 8
// 1176.959 us; speedup vs baseline: 6.5608x; 1.0298x over previous
//
#include <hip/hip_runtime.h>
#include <hip/hip_bf16.h>
#include <hip/hip_fp16.h>

#define B_ 128
#define S_ 128
#define I_ 300
#define IP_ 320
#define H_ 1024
#define C_ 2

typedef __attribute__((ext_vector_type(8))) short short8;
typedef __attribute__((ext_vector_type(4))) float f32x4;

__device__ inline short f2b(float f) {
    union { __hip_bfloat16 h; unsigned short s; } cv;
    cv.h = __float2bfloat16(f);
    return (short)cv.s;
}

__global__ __launch_bounds__(256) void prep_bias(
    const float* __restrict__ b_ih, const float* __restrict__ b_hh,
    float* __restrict__ bias)
{
    int i = blockIdx.x * 256 + threadIdx.x;
    if (i < 4 * H_) bias[i] = b_ih[i] + b_hh[i];
}

// W_ihp bf16 [4096][320], zero-padded cols 300..319
__global__ __launch_bounds__(256) void prep_wih(
    const float* __restrict__ W_ih, unsigned short* __restrict__ Wp)
{
    int idx = blockIdx.x * 256 + threadIdx.x;
    if (idx >= 4096 * IP_) return;
    int row = idx / IP_, k = idx - row * IP_;
    Wp[idx] = (k < I_) ? (unsigned short)f2b(W_ih[row * I_ + k]) : 0;
}

// xe bf16 [S][B][320]: gathered embedding rows, zero-padded
__global__ __launch_bounds__(256) void prep_xe(
    const int* __restrict__ x, const float* __restrict__ embed_W,
    unsigned short* __restrict__ xe)
{
    int idx = blockIdx.x * 256 + threadIdx.x;
    if (idx >= S_ * B_ * IP_) return;
    int k = idx % IP_;
    int tb = idx / IP_;
    int b = tb % B_, t = tb / B_;
    int row = x[b * S_ + t];
    xe[idx] = (k < I_) ? (unsigned short)f2b(embed_W[(size_t)row * I_ + k]) : 0;
}

// Wfrag: W_hh in per-lane MFMA B-fragment order (R6/R7-proven layout)
__global__ __launch_bounds__(256) void prep_wfrag(
    const float* __restrict__ W_hh, unsigned short* __restrict__ Wfrag)
{
    int idx = blockIdx.x * 256 + threadIdx.x;   // 0 .. 524287
    const int lane = idx & 63;
    const int f    = (idx >> 6) & 31;
    const int wid  = (idx >> 11) & 3;
    const int ug   = idx >> 13;
    const int row  = wid * H_ + ug * 16 + (lane & 15);
    const int k0   = f * 32 + (lane >> 4) * 8;
    const float* src = W_hh + (size_t)row * H_ + k0;
    unsigned short* dst = Wfrag + (size_t)idx * 8;
#pragma unroll
    for (int j = 0; j < 8; ++j)
        dst[j] = (unsigned short)f2b(src[j]);
}

// ---------------------------------------------------------------------------
// gates in FRAGMENT layout (half bits):
//   idx = t*524288 + bx*16384 + nt*2048 + fr*128 + fq*32 + wp*8 + mt*4 + r
//   holds gate for col n = bx*128+nt*16+fr, batch m = wp*32+mt*16+fq*4+r.
// ---------------------------------------------------------------------------
__global__ __launch_bounds__(256) void gemm_ih(
    const unsigned short* __restrict__ xe,   // [S][B][320] bf16
    const unsigned short* __restrict__ Wp,   // [4096][320] bf16
    const float* __restrict__ bias,          // [4096]
    unsigned short* __restrict__ gates)      // frag layout, half bits
{
    const int tid = threadIdx.x;
    const int wid = tid >> 6, lane = tid & 63;
    const int fr = lane & 15, fq = lane >> 4;
    const int bx = blockIdx.x;            // n-tile base bx*128
    const int t  = blockIdx.y;

    __shared__ alignas(16) unsigned short As_[128][40];
    __shared__ alignas(16) unsigned short Bs_[128][40];

    const int sr = tid >> 1;
    const int sc = (tid & 1) * 16;
    const unsigned short* arow = xe + ((size_t)t * B_ + sr) * IP_;
    const unsigned short* brow = Wp + (size_t)(bx * 128 + sr) * IP_;

    f32x4 acc[2][8] = {};

    for (int kc = 0; kc < 10; ++kc) {
        __syncthreads();
        const int k0 = kc * 32 + sc;
        *(short8*)&As_[sr][sc]     = *(const short8*)(arow + k0);
        *(short8*)&As_[sr][sc + 8] = *(const short8*)(arow + k0 + 8);
        *(short8*)&Bs_[sr][sc]     = *(const short8*)(brow + k0);
        *(short8*)&Bs_[sr][sc + 8] = *(const short8*)(brow + k0 + 8);
        __syncthreads();
        short8 bfrag[8];
#pragma unroll
        for (int nt = 0; nt < 8; ++nt)
            bfrag[nt] = *(const short8*)&Bs_[nt * 16 + fr][fq * 8];
#pragma unroll
        for (int mt = 0; mt < 2; ++mt) {
            short8 a = *(const short8*)&As_[wid * 32 + mt * 16 + fr][fq * 8];
#pragma unroll
            for (int nt = 0; nt < 8; ++nt)
                acc[mt][nt] = __builtin_amdgcn_mfma_f32_16x16x32_bf16(
                    a, bfrag[nt], acc[mt][nt], 0, 0, 0);
        }
    }
    // epilogue: one coalesced 16-B store per nt
    unsigned short* gbase = gates + (size_t)t * 524288 + (size_t)bx * 16384
                          + fr * 128 + fq * 32 + wid * 8;
#pragma unroll
    for (int nt = 0; nt < 8; ++nt) {
        const float bs = bias[bx * 128 + nt * 16 + fr];
        short8 pk;
#pragma unroll
        for (int r = 0; r < 4; ++r) {
            pk[r]     = (short)__half_as_ushort(__float2half(acc[0][nt][r] + bs));
            pk[4 + r] = (short)__half_as_ushort(__float2half(acc[1][nt][r] + bs));
        }
        *(short8*)(gbase + nt * 2048) = pk;
    }
}

// ---------------------------------------------------------------------------
// Persistent recurrent kernel, v7:
//   LDS back inside the PROVEN envelope: As 67,072 + Gs2 8,576 = 75,648 B
//   (rounds 6/7's 100,352 B never launched cooperatively -> silent fail).
//   - 2-way K-split: wave wid -> gate-pair gp = wid>>1 (gates 2gp,2gp+1),
//     K-half kh = wid&1 (k in [kh*512, kh*512+512)). A-reads 64->32
//     ds_read_b128/wave. Partials exchanged in HALF via Gs2[2][32][67].
//     Each wave folds gate wid's precomputed ih fragment into its partial
//     for gate wid = 2gp+kh (member of its pair; added exactly once).
//     All register indexing static (named acc00..acc11, uniform branches).
//   - 2-RT flag-matrix barrier: producer stores t+1 into flags[bg][c][ug]
//     for each consumer c (fire-and-forget); consumer polls ITS OWN 256-B
//     row (sole reader per line, no RMW, monotonic).
//   - c state in registers; h[t+1] via agent-scope stores to LLC (proven).
// ---------------------------------------------------------------------------
__global__ __launch_bounds__(256, 1) void lstm_persistent(
    const unsigned short* __restrict__ Wfrag,
    const unsigned short* __restrict__ gates,   // frag layout, half bits
    __hip_bfloat16* __restrict__ hs,            // [S+1,B,H]
    unsigned int* __restrict__ flags)           // [4][64][64] flag matrix
{
    const int tid  = threadIdx.x;
    const int wid  = tid >> 6;
    const int lane = tid & 63;
    const int ug = blockIdx.x;
    const int bg = blockIdx.y;
    const int n0 = ug * 16;
    const int fr = lane & 15, fq = lane >> 4;
    const int m0g = bg * 32;
    const int gp = wid >> 1;          // gate pair: gates 2gp, 2gp+1
    const int kh = wid & 1;           // K-half: [kh*512, kh*512+512)

    __shared__ alignas(16) unsigned short As[32][1048];  // h slab 32x1024
    __shared__ __half Gs2[2][32][67];                     // half partials

    // ---- W fragments: 2 gates x 16 k-chunks of this wave's K-half ----
    short8 bfrA[16], bfrB[16];
    {
        const unsigned short* pA = Wfrag +
            ((size_t)((ug * 4 + 2 * gp) * 32 + kh * 16) * 64 + lane) * 8;
        const unsigned short* pB = Wfrag +
            ((size_t)((ug * 4 + 2 * gp + 1) * 32 + kh * 16) * 64 + lane) * 8;
#pragma unroll
        for (int j = 0; j < 16; ++j) {
            bfrA[j] = *(const short8*)(pA + (size_t)j * 512);
            bfrB[j] = *(const short8*)(pB + (size_t)j * 512);
        }
    }

    // cell-state registers: thread owns batch row m0g+cm2, units u0,u0+1
    const int cm2 = tid >> 3, up = tid & 7;
    const int u0 = 2 * up;
    float2 cc;
    cc.x = 0.f;
    cc.y = 0.f;

    // fused ih-gates base (per-lane, gate = wid, t-stride 524288) — proven
    const unsigned short* gbase = gates
        + (size_t)(wid * 8 + (ug >> 3)) * 16384
        + (size_t)(ug & 7) * 2048 + fr * 128 + fq * 32 + bg * 8;

    const unsigned short* a0p = &As[fr][kh * 512 + fq * 8];
    const unsigned short* a1p = &As[16 + fr][kh * 512 + fq * 8];

    // flag matrix: row [bg][ug][0..63] read ONLY by this block (256 B).
    unsigned int* row_poll = flags + bg * 4096 + ug * 64 + lane;  // consumer
    unsigned int* col_st   = flags + bg * 4096 + lane * 64 + ug;  // producer

    union GU { short8 v; __half h[8]; };
    GU gcur, gnxt;
    gcur.v = *(const short8*)gbase;           // t = 0 gates
    gnxt = gcur;

    for (int t = 0; t < S_; ++t) {
        // ---- stage h_prev slab [32][1024] to LDS (normal cached loads) ----
        {
            const __hip_bfloat16* hprev =
                hs + (size_t)t * (B_ * H_) + (size_t)m0g * H_;
#pragma unroll
            for (int i = 0; i < 16; ++i) {
                const int e = i * 256 + tid;          // 16B-chunk id
                const int r = e >> 7, ch = (e & 127) * 8;
                *(short8*)&As[r][ch] = *(const short8*)(hprev + r * H_ + ch);
            }
        }
        __syncthreads();

        // ---- K-half MFMAs: 32 ds_reads, 64 MFMAs per wave ----
        f32x4 acc00 = {0.f,0.f,0.f,0.f}, acc01 = {0.f,0.f,0.f,0.f};
        f32x4 acc10 = {0.f,0.f,0.f,0.f}, acc11 = {0.f,0.f,0.f,0.f};
#pragma unroll
        for (int j = 0; j < 16; ++j) {
            short8 a0 = *(const short8*)(a0p + j * 32);
            short8 a1 = *(const short8*)(a1p + j * 32);
            acc00 = __builtin_amdgcn_mfma_f32_16x16x32_bf16(a0, bfrA[j], acc00, 0, 0, 0);
            acc01 = __builtin_amdgcn_mfma_f32_16x16x32_bf16(a1, bfrA[j], acc01, 0, 0, 0);
            acc10 = __builtin_amdgcn_mfma_f32_16x16x32_bf16(a0, bfrB[j], acc10, 0, 0, 0);
            acc11 = __builtin_amdgcn_mfma_f32_16x16x32_bf16(a1, bfrB[j], acc11, 0, 0, 0);
        }

        // fold gate wid's ih fragment (wid = 2gp+kh: kh==0 -> gate 2gp is
        // local slot A; kh==1 -> gate 2gp+1 is local slot B). Uniform branch,
        // static register indices.
        if (kh == 0) {
#pragma unroll
            for (int r = 0; r < 4; ++r) {
                acc00[r] += __half2float(gcur.h[r]);
                acc01[r] += __half2float(gcur.h[4 + r]);
            }
        } else {
#pragma unroll
            for (int r = 0; r < 4; ++r) {
                acc10[r] += __half2float(gcur.h[r]);
                acc11[r] += __half2float(gcur.h[4 + r]);
            }
        }

        // ---- write partials: Gs2[kh][m][gate*16+u] (half) ----
        {
            const int rb = fq * 4;
            const int cA = gp * 32 + fr;        // gate 2gp
            const int cB = cA + 16;             // gate 2gp+1
#pragma unroll
            for (int r = 0; r < 4; ++r) {
                Gs2[kh][rb + r][cA]      = __float2half(acc00[r]);
                Gs2[kh][16 + rb + r][cA] = __float2half(acc01[r]);
                Gs2[kh][rb + r][cB]      = __float2half(acc10[r]);
                Gs2[kh][16 + rb + r][cB] = __float2half(acc11[r]);
            }
        }

        // ---- prefetch next step's gates: hides under cell-update+barrier
        if (t + 1 < S_)
            gnxt.v = *(const short8*)(gbase + (size_t)(t + 1) * 524288);

        __syncthreads();

        // ---- cell update (ALL 256 threads): 2-way reduce + reg c ----
        {
            float G[4][2];
#pragma unroll
            for (int g = 0; g < 4; ++g) {
                G[g][0] = __half2float(Gs2[0][cm2][g * 16 + u0])
                        + __half2float(Gs2[1][cm2][g * 16 + u0]);
                G[g][1] = __half2float(Gs2[0][cm2][g * 16 + u0 + 1])
                        + __half2float(Gs2[1][cm2][g * 16 + u0 + 1]);
            }
            float si0 = 1.f / (1.f + __expf(-G[0][0]));
            float sf0 = 1.f / (1.f + __expf(-G[1][0]));
            float so0 = 1.f / (1.f + __expf(-G[3][0]));
            float si1 = 1.f / (1.f + __expf(-G[0][1]));
            float sf1 = 1.f / (1.f + __expf(-G[1][1]));
            float so1 = 1.f / (1.f + __expf(-G[3][1]));
            cc.x = sf0 * cc.x + si0 * tanhf(G[2][0]);
            cc.y = sf1 * cc.y + si1 * tanhf(G[2][1]);
            float h0 = so0 * tanhf(cc.x);
            float h1 = so1 * tanhf(cc.y);
            unsigned int hv =
                (unsigned int)(unsigned short)f2b(h0) |
                ((unsigned int)(unsigned short)f2b(h1) << 16);
            unsigned int* dst = (unsigned int*)
                (hs + (size_t)(t + 1) * (B_ * H_) +
                 (size_t)(m0g + cm2) * H_ + n0) + up;
            // agent-scope store: bypasses L1/L2, lands at coherent LLC
            __hip_atomic_store(dst, hv, __ATOMIC_RELAXED,
                               __HIP_MEMORY_SCOPE_AGENT);
        }

        if (t < S_ - 1) {
            // drain h stores (and gih prefetch) to the coherence point
            asm volatile("s_waitcnt vmcnt(0)" ::: "memory");
            __syncthreads();   // all waves drained
            if (wid == 0) {
                const unsigned int tgt = (unsigned int)(t + 1);
                // arrive: one slot per consumer (fire-and-forget; next
                // step's vmcnt(0) orders same-address reuse)
                __hip_atomic_store(col_st, tgt, __ATOMIC_RELAXED,
                                   __HIP_MEMORY_SCOPE_AGENT);
                // wait: poll OWN 256-B row, sole reader, coalesced
                for (;;) {
                    unsigned int v = __hip_atomic_load(
                        row_poll, __ATOMIC_RELAXED, __HIP_MEMORY_SCOPE_AGENT);
                    if (__all((int)(v >= tgt))) break;
                    __builtin_amdgcn_s_sleep(1);
                }
            }
            asm volatile("" ::: "memory");  // no loads hoisted above the spin
            __syncthreads();
        }
        gcur = gnxt;
    }
}

// ---------------------------------------------------------------------------
// FALLBACK per-timestep kernel (harness-proven baseline structure) — used
// only if the cooperative launch is rejected. Identical math/layouts.
// ---------------------------------------------------------------------------
__global__ __launch_bounds__(256, 1) void lstm_step_v3(
    const unsigned short* __restrict__ Wfrag,
    const unsigned short* __restrict__ gates,   // frag layout, half bits
    float* __restrict__ c_state,                // [B,H] fp32
    __hip_bfloat16* __restrict__ hs,            // [S+1,B,H]
    int t)
{
    const int tid  = threadIdx.x;
    const int wid  = tid >> 6;            // wave = gate
    const int lane = tid & 63;
    const int ug = blockIdx.x;
    const int bg = blockIdx.y;
    const int n0 = ug * 16;
    const int fr = lane & 15, fq = lane >> 4;
    const int m0g = bg * 32;

    __shared__ alignas(16) unsigned short As[32][1048];
    __shared__ float Gs[32][65];

    short8 bfr[32];
    {
        const unsigned short* wf =
            Wfrag + ((size_t)((ug * 4 + wid) * 32) * 64 + lane) * 8;
#pragma unroll
        for (int f = 0; f < 32; ++f)
            bfr[f] = *(const short8*)(wf + (size_t)f * 512);
    }

    union { short8 v; __half h[8]; } gih;
    {
        const unsigned short* gp = gates + (size_t)t * 524288
            + (size_t)(wid * 8 + (ug >> 3)) * 16384
            + (size_t)(ug & 7) * 2048 + fr * 128 + fq * 32 + bg * 8;
        gih.v = *(const short8*)gp;
    }

    {
        const __hip_bfloat16* hprev =
            hs + (size_t)t * (B_ * H_) + (size_t)m0g * H_;
#pragma unroll
        for (int i = 0; i < 16; ++i) {
            const int e = i * 256 + tid;
            const int r = e >> 7, ch = (e & 127) * 8;
            *(short8*)&As[r][ch] = *(const short8*)(hprev + r * H_ + ch);
        }
    }
    __syncthreads();

    f32x4 acc0 = {0.f,0.f,0.f,0.f}, acc1 = {0.f,0.f,0.f,0.f};
    {
        const unsigned short* a0p = &As[fr][fq * 8];
        const unsigned short* a1p = &As[16 + fr][fq * 8];
#pragma unroll
        for (int f = 0; f < 32; ++f) {
            short8 a0 = *(const short8*)(a0p + f * 32);
            short8 a1 = *(const short8*)(a1p + f * 32);
            acc0 = __builtin_amdgcn_mfma_f32_16x16x32_bf16(a0, bfr[f], acc0, 0, 0, 0);
            acc1 = __builtin_amdgcn_mfma_f32_16x16x32_bf16(a1, bfr[f], acc1, 0, 0, 0);
        }
    }

#pragma unroll
    for (int r = 0; r < 4; ++r) {
        acc0[r] += __half2float(gih.h[r]);
        acc1[r] += __half2float(gih.h[4 + r]);
    }

    {
        const int col = wid * 16 + fr;
        const int rb = fq * 4;
#pragma unroll
        for (int r = 0; r < 4; ++r) {
            Gs[rb + r][col]      = acc0[r];
            Gs[16 + rb + r][col] = acc1[r];
        }
    }
    __syncthreads();

    {
        const int cm2 = tid >> 3, up = tid & 7;
        const int u0 = 2 * up;
        float gi0 = Gs[cm2][u0],      gi1 = Gs[cm2][u0 + 1];
        float gf0 = Gs[cm2][16 + u0], gf1 = Gs[cm2][16 + u0 + 1];
        float gg0 = Gs[cm2][32 + u0], gg1 = Gs[cm2][32 + u0 + 1];
        float go0 = Gs[cm2][48 + u0], go1 = Gs[cm2][48 + u0 + 1];
        float si0 = 1.f / (1.f + __expf(-gi0));
        float sf0 = 1.f / (1.f + __expf(-gf0));
        float so0 = 1.f / (1.f + __expf(-go0));
        float si1 = 1.f / (1.f + __expf(-gi1));
        float sf1 = 1.f / (1.f + __expf(-gf1));
        float so1 = 1.f / (1.f + __expf(-go1));
        float* cp = c_state + (size_t)(m0g + cm2) * H_ + n0 + u0;
        float2 ccc = *(float2*)cp;
        ccc.x = sf0 * ccc.x + si0 * tanhf(gg0);
        ccc.y = sf1 * ccc.y + si1 * tanhf(gg1);
        *(float2*)cp = ccc;
        float h0 = so0 * tanhf(ccc.x);
        float h1 = so1 * tanhf(ccc.y);
        unsigned int hv =
            (unsigned int)(unsigned short)f2b(h0) |
            ((unsigned int)(unsigned short)f2b(h1) << 16);
        unsigned int* dst = (unsigned int*)
            (hs + (size_t)(t + 1) * (B_ * H_) +
             (size_t)(m0g + cm2) * H_ + n0) + up;
        *dst = hv;
    }
}

// ---------------------------------------------------------------------------
// Head: one wave per (b,t): out = h . lin_W^T + lin_b, masked by lengths.
// ---------------------------------------------------------------------------
__global__ __launch_bounds__(256) void final_linear(
    const __hip_bfloat16* __restrict__ hs,
    const float* __restrict__ lin_W,
    const float* __restrict__ lin_b,
    const int* __restrict__ lengths,
    float* __restrict__ out)
{
    const int wid  = threadIdx.x >> 6;
    const int lane = threadIdx.x & 63;
    const int p = blockIdx.x * 4 + wid;
    const int b = p >> 7;
    const int t = p & 127;
    const __hip_bfloat16* h =
        hs + (size_t)(t + 1) * (B_ * H_) + (size_t)b * H_;
    float s0 = 0.f, s1 = 0.f;
#pragma unroll
    for (int i = 0; i < 16; ++i) {
        int n = lane + 64 * i;
        float hv = __bfloat162float(h[n]);
        s0 += hv * lin_W[n];
        s1 += hv * lin_W[H_ + n];
    }
#pragma unroll
    for (int off = 32; off > 0; off >>= 1) {
        s0 += __shfl_down(s0, off);
        s1 += __shfl_down(s1, off);
    }
    if (lane == 0) {
        float* o = out + (size_t)p * 2;
        if (t < lengths[b]) {
            o[0] = s0 + lin_b[0];
            o[1] = s1 + lin_b[1];
        } else {
            o[0] = 1.0f;
            o[1] = 0.0f;
        }
    }
}

extern "C" void kernel_launch(void* const* d_in, const int* in_sizes, int n_in,
                              void* d_out, int out_size, void* d_ws,
                              size_t ws_size, hipStream_t stream) {
    const int* x              = (const int*)d_in[0];
    const int* lengths        = (const int*)d_in[1];
    const float* embed_W      = (const float*)d_in[2];
    const float* W_ih         = (const float*)d_in[3];
    const float* W_hh         = (const float*)d_in[4];
    const float* b_ih         = (const float*)d_in[5];
    const float* b_hh         = (const float*)d_in[6];
    const float* lin_W        = (const float*)d_in[7];
    const float* lin_b        = (const float*)d_in[8];
    float* out                = (float*)d_out;

    // ws layout (total 176,963,584 = round-0 proven footprint):
    //   hs bf16 [S+1,B,H]      @ 0            (33,816,576)
    //   gates half (frag)      @ 33,816,576   (134,217,728)
    //   bias fp32 [4096]       @ 168,034,304  (16,384)
    //   Wfrag bf16             @ 168,050,688  (8,388,608)
    //   flags u32[4][64][64] / c_state fp32[B,H]  @ 176,439,296 (524,288)
    //     (UNION: flags used by coop path; c_state by fallback path —
    //      mutually exclusive; one 512KB memset zeroes both)
    //   xe bf16 [S,B,320]      @ hs+262,144   (10,485,760) [alias, consumed
    //   W_ihp bf16 [4096,320]  @ hs+10,747,904 (2,621,440)  before steps]
    char* ws = (char*)d_ws;
    __hip_bfloat16* hs    = (__hip_bfloat16*)(ws + 0);
    unsigned short* gates = (unsigned short*)(ws + 33816576);
    float* bias           = (float*)(ws + 168034304);
    unsigned short* Wfrag = (unsigned short*)(ws + 168050688);
    unsigned int* flags   = (unsigned int*)(ws + 176439296);
    float* c_state        = (float*)(ws + 176439296);
    unsigned short* xe    = (unsigned short*)(ws + 262144);
    unsigned short* Wp    = (unsigned short*)(ws + 10747904);

    prep_bias<<<16, 256, 0, stream>>>(b_ih, b_hh, bias);
    prep_wih<<<(4096 * IP_ + 255) / 256, 256, 0, stream>>>(W_ih, Wp);
    prep_xe<<<(S_ * B_ * IP_ + 255) / 256, 256, 0, stream>>>(x, embed_W, xe);
    prep_wfrag<<<2048, 256, 0, stream>>>(W_hh, Wfrag);
    (void)hipMemsetAsync(hs, 0, (size_t)B_ * H_ * sizeof(__hip_bfloat16), stream);
    (void)hipMemsetAsync(ws + 176439296, 0, 524288, stream);

    gemm_ih<<<dim3(32, 128), 256, 0, stream>>>(xe, Wp, bias, gates);

    // cooperative launch (residency guarantee); CHECKED — fall back to the
    // proven per-step dispatch path if the runtime rejects it.
    hipError_t ce;
    {
        void* kargs[4];
        kargs[0] = (void*)&Wfrag;
        kargs[1] = (void*)&gates;
        kargs[2] = (void*)&hs;
        kargs[3] = (void*)&flags;
        ce = hipLaunchCooperativeKernel((const void*)lstm_persistent,
                                        dim3(64, 4), dim3(256, 1, 1),
                                        kargs, 0, stream);
    }
    if (ce != hipSuccess) {
        for (int t = 0; t < S_; ++t) {
            lstm_step_v3<<<dim3(64, 4), 256, 0, stream>>>(
                Wfrag, gates, c_state, hs, t);
        }
    }

    final_linear<<<dim3((B_ * S_) / 4), 256, 0, stream>>>(
        hs, lin_W, lin_b, lengths, out);
}